// Round 10
// baseline (179.730 us; speedup 1.0000x reference)
//
#include <hip/hip_runtime.h>
#include <hip/hip_bf16.h>
#include <math.h>

#define NCC 64
#define CSC 64
#define DC 64
#define S 72            // bf16 LDS row stride (144 B rows)
#define SO 68           // outb fp32 row stride
#define EPSF 1e-6f
#define LDS_BYTES 84224

typedef __attribute__((ext_vector_type(8))) short bf16x8;   // MFMA A/B frag
typedef __attribute__((ext_vector_type(4))) float f32x4;    // MFMA C/D frag
typedef __attribute__((ext_vector_type(4))) short short4v;
typedef __attribute__((ext_vector_type(2))) short short2v;

static __device__ __forceinline__ short cvt_bf16(float x) { // HW RNE
    union { __hip_bfloat16 b; short s; } u;
    u.b = __float2bfloat16(x);
    return u.s;
}
static __device__ __forceinline__ float bf16_to_f(unsigned hw) {
    union { unsigned u; float f; } v; v.u = hw << 16;
    return v.f;
}

// 16-lane sum via DPP row rotations (VALU-only; DPP row = 16 lanes).
#define DPP_ROR_ADD(v, N)                                                     \
    do {                                                                      \
        union { float f; int i; } _u, _r;                                     \
        _u.f = (v);                                                           \
        _r.i = __builtin_amdgcn_mov_dpp(_u.i, 0x120 + (N), 0xF, 0xF, true);   \
        (v) += _r.f;                                                          \
    } while (0)

static __device__ __forceinline__ float red16(float v) {
    DPP_ROR_ADD(v, 1);
    DPP_ROR_ADD(v, 2);
    DPP_ROR_ADD(v, 4);
    DPP_ROR_ADD(v, 8);
    return v;
}

__global__ __launch_bounds__(512, 1) void ttt_kernel(
    const float* __restrict__ xk, const float* __restrict__ xv,
    const float* __restrict__ weight, const float* __restrict__ bias,
    const float* __restrict__ gamma, const float* __restrict__ beta,
    const float* __restrict__ theta, const float* __restrict__ theta_bias,
    const float* __restrict__ alpha, float* __restrict__ out)
{
    extern __shared__ char sb[];
    auto xs_rm = (short (*)[CSC][S])(sb);             // [2][64][S] xk row-major
    auto xsT   = (short (*)[DC][S]) (sb + 18432);     // [2][64][S] xk^T
    auto gsT   = (short (*)[S])     (sb + 36864);     // gs^T [e][k]
    auto Gr    = (short (*)[S])     (sb + 46080);     // Gram+1 (ones-trick)
    auto Wtb   = (short (*)[S])     (sb + 55296);     // W [e][d]
    auto dbp   = (float (*)[DC])    (sb + 64512);     // [8][64] db partials
    auto outb  = (float (*)[SO])    (sb + 66560);     // [64][SO] out, [e][k] fp32
    auto bs    = (float*)           (sb + 83968);     // [64] bias state, idx 4*la+n

    const int t   = threadIdx.x;
    const int w   = t >> 6;           // wave 0..7
    const bool lo = (w < 4);
    const int ws  = w & 3;
    const int l   = t & 63;
    const int g   = l >> 4, la = l & 15;
    const int r0  = 16*ws + 4*g;
    const int io  = lo ? 0 : 2;       // epilogue row-pair offset
    const int ts  = 64*ws + l;        // per-half thread id (staging)
    const int bh  = blockIdx.x;
    const int h   = bh & 15;

    const size_t bh_off = (size_t)bh * NCC*CSC*DC;
    const float* xkb = xk + bh_off;
    const float* xvb = xv + bh_off;
    float*       ob  = out + bh_off;

    // constants
    float gam[4], bet[4], thv[4];
#pragma unroll
    for (int n = 0; n < 4; ++n) {
        gam[n] = gamma[h*DC + 16*n + la];
        bet[n] = beta [h*DC + 16*n + la];
        thv[n] = theta[h*DC + 16*n + la];
    }
    const float tb = theta_bias[h];
    float tokk[2];
#pragma unroll
    for (int ii = 0; ii < 2; ++ii) {
        int r = r0 + io + ii;
        tokk[ii] = fmaxf(1.0f/(float)(r+1) + alpha[r], 0.0f);
    }

    // bias state in LDS: bs[4*la'+n'] = bias[16n'+la']
    if (t < DC) bs[t] = bias[h*DC + 16*(t & 3) + (t >> 2)];

    float Wreg[4][4];                 // low half: W state
    float4 xl[4];                     // low half: rm staging regs
    float xkh[4][4];                  // low half: xsT staging rows
    float xvg[2][4];                  // epilogue xv rows (both halves)

#pragma unroll
    for (int ii = 0; ii < 2; ++ii)
#pragma unroll
        for (int n = 0; n < 4; ++n)
            xvg[ii][n] = xvb[(r0+io+ii)*DC + 16*n + la];

    if (lo) {
        const float* wg = weight + h*DC*DC;
#pragma unroll
        for (int i = 0; i < 4; ++i)
#pragma unroll
            for (int n = 0; n < 4; ++n)
                Wreg[i][n] = wg[(r0+i)*DC + 16*n + la];
#pragma unroll
        for (int n = 0; n < 4; ++n) {
            short4v sv;
#pragma unroll
            for (int i = 0; i < 4; ++i) sv[i] = cvt_bf16(Wreg[i][n]);
            *(short4v*)&Wtb[16*n + la][r0] = sv;
        }
#pragma unroll
        for (int i4 = 0; i4 < 4; ++i4) xl[i4] = ((const float4*)xkb)[ts + 256*i4];
#pragma unroll
        for (int i = 0; i < 4; ++i)
#pragma unroll
            for (int n = 0; n < 4; ++n)
                xkh[i][n] = xkb[(r0+i)*DC + 16*n + la];
#pragma unroll
        for (int i4 = 0; i4 < 4; ++i4) {    // stage chunk 0 row-major
            int f = ts + 256*i4, k = f >> 4, j = f & 15;
            short4v s4;
            s4[0]=cvt_bf16(xl[i4].x); s4[1]=cvt_bf16(xl[i4].y);
            s4[2]=cvt_bf16(xl[i4].z); s4[3]=cvt_bf16(xl[i4].w);
            *(short4v*)&xs_rm[0][k][4*j] = s4;
        }
#pragma unroll
        for (int n = 0; n < 4; ++n) {       // stage chunk 0 transposed
            short4v sv;
#pragma unroll
            for (int i = 0; i < 4; ++i) sv[i] = cvt_bf16(xkh[i][n]);
            *(short4v*)&xsT[0][16*n + la][r0] = sv;
        }
    }
    __syncthreads();

    for (int c = 0; c < NCC; ++c) {
        const int cb = c & 1, nb = cb ^ 1;
        const bool pf = (c + 1 < NCC);

        // ---- P1 head: read b(c); store out(c-1) coalesced (overlaps z) ----
        f32x4 bold = *(const f32x4*)&bs[4*la];
        if (c > 0) {
            float* ocp = ob + (c-1)*CSC*DC;
            const int kk = 4*w + (l >> 4);        // row 0..31 (+32 second pass)
            const int e0 = 4*(l & 15);
#pragma unroll
            for (int p = 0; p < 2; ++p) {
                int k2 = kk + 32*p;
                float4 v;
                v.x = outb[e0+0][k2]; v.y = outb[e0+1][k2];
                v.z = outb[e0+2][k2]; v.w = outb[e0+3][k2];
                *(float4*)(ocp + k2*DC + e0) = v;
            }
        }

        // ---- P1: z = xs@W (all waves) ----
        const bf16x8 a0 = *(const bf16x8*)&xs_rm[cb][16*ws + la][8*g];
        const bf16x8 a1 = *(const bf16x8*)&xs_rm[cb][16*ws + la][32 + 8*g];
        f32x4 zt[4];
#pragma unroll
        for (int n = 0; n < 4; ++n) {
            bf16x8 w0 = *(const bf16x8*)&Wtb[16*n + la][8*g];
            bf16x8 w1 = *(const bf16x8*)&Wtb[16*n + la][32 + 8*g];
            f32x4 zz = {0.f,0.f,0.f,0.f};
            zz = __builtin_amdgcn_mfma_f32_16x16x32_bf16(a0, w0, zz, 0,0,0);
            zz = __builtin_amdgcn_mfma_f32_16x16x32_bf16(a1, w1, zz, 0,0,0);
            zt[n] = zz;
        }
        if (!lo) {                    // Gram+1 (ones-trick) on high half
#pragma unroll
            for (int n = 0; n < 4; ++n) {
                bf16x8 b0 = *(const bf16x8*)&xs_rm[cb][16*n + la][8*g];
                bf16x8 b1 = *(const bf16x8*)&xs_rm[cb][16*n + la][32 + 8*g];
                f32x4 cc = {0.f,0.f,0.f,0.f};
                cc = __builtin_amdgcn_mfma_f32_16x16x32_bf16(a0, b0, cc, 0,0,0);
                cc = __builtin_amdgcn_mfma_f32_16x16x32_bf16(a1, b1, cc, 0,0,0);
                short4v sg;
#pragma unroll
                for (int i = 0; i < 4; ++i) sg[i] = cvt_bf16(cc[i] + 1.0f);
                *(short4v*)&Gr[16*n + la][r0] = sg;
            }
        }

        // epilogue xk rows from xsT (b32, conflict-free)
        float xkq[2][4];
#pragma unroll
        for (int n = 0; n < 4; ++n) {
            unsigned pk = *(const unsigned*)&xsT[cb][16*n + la][r0 + io];
            xkq[0][n] = bf16_to_f(pk & 0xFFFFu);
            xkq[1][n] = bf16_to_f(pk >> 16);
        }

        // VMEM prefetch for chunk c+1 (latency spans epilogue + barrier)
        float xvN[2][4];
        if (pf) {
            const float* xvn = xvb + (c+1)*CSC*DC;
#pragma unroll
            for (int ii = 0; ii < 2; ++ii)
#pragma unroll
                for (int n = 0; n < 4; ++n)
                    xvN[ii][n] = xvn[(r0+io+ii)*DC + 16*n + la];
            if (lo) {
                const float* xkn = xkb + (c+1)*CSC*DC;
#pragma unroll
                for (int i4 = 0; i4 < 4; ++i4) xl[i4] = ((const float4*)xkn)[ts + 256*i4];
#pragma unroll
                for (int i = 0; i < 4; ++i)
#pragma unroll
                    for (int n = 0; n < 4; ++n)
                        xkh[i][n] = xkn[(r0+i)*DC + 16*n + la];
            }
        }

        // select this half's 2 epilogue rows
        float zrow[2][4];
        if (lo) {
#pragma unroll
            for (int n = 0; n < 4; ++n) { zrow[0][n] = zt[n][0]; zrow[1][n] = zt[n][1]; }
        } else {
#pragma unroll
            for (int n = 0; n < 4; ++n) { zrow[0][n] = zt[n][2]; zrow[1][n] = zt[n][3]; }
        }

        // ---- epilogue: 2 rows/thread, all 8 waves ----
        float gsv[2][4];
#pragma unroll
        for (int ii = 0; ii < 2; ++ii) {
            float z4[4];
#pragma unroll
            for (int n = 0; n < 4; ++n) z4[n] = zrow[ii][n] + bold[n];
            float szz = red16(z4[0]*z4[0] + z4[1]*z4[1] + z4[2]*z4[2] + z4[3]*z4[3]);
            float sz  = red16(z4[0] + z4[1] + z4[2] + z4[3]);
            float thd = red16(xkq[ii][0]*thv[0] + xkq[ii][1]*thv[1] +
                              xkq[ii][2]*thv[2] + xkq[ii][3]*thv[3]);
            float mu   = sz * (1.0f/DC);
            float var  = szz*(1.0f/DC) - mu*mu;
            float rstd = rsqrtf(var + EPSF);
            float ex   = __expf(-(thd + tb));
            float lr   = __builtin_amdgcn_rcpf(1.0f + ex);
            float eta  = tokk[ii]*lr*(1.0f/DC);
            float xh[4], gxh[4], a1v = 0.f, a2v = 0.f;
#pragma unroll
            for (int n = 0; n < 4; ++n) {
                xh[n] = (z4[n]-mu)*rstd;
                float y  = fmaf(gam[n], xh[n], bet[n]);
                float go = y - xvg[ii][n] + xkq[ii][n];
                gxh[n] = go*gam[n];
                a1v += gxh[n];
                a2v = fmaf(gxh[n], xh[n], a2v);
            }
            float s1 = red16(a1v), s2 = red16(a2v);
            float sc = rstd*(1.0f/DC)*eta;
#pragma unroll
            for (int n = 0; n < 4; ++n)
                gsv[ii][n] = (64.f*gxh[n] - s1 - xh[n]*s2)*sc;
        }
#pragma unroll
        for (int n = 0; n < 4; ++n) {       // gsT b32 pack (2 rows)
            short2v sg;
            sg[0] = cvt_bf16(gsv[0][n]);
            sg[1] = cvt_bf16(gsv[1][n]);
            *(short2v*)&gsT[16*n + la][r0 + io] = sg;
        }
        float dbl[4];
#pragma unroll
        for (int n = 0; n < 4; ++n) {       // per-wave db partial
            float dd = gsv[0][n] + gsv[1][n];
            dd += __shfl_xor(dd, 16);
            dd += __shfl_xor(dd, 32);
            dbl[n] = dd;
        }
        if (l < 16) {
            f32x4 dv = {dbl[0], dbl[1], dbl[2], dbl[3]};
            *(f32x4*)&dbp[w][4*la] = dv;
        }
        __syncthreads();    // B: gsT, Gr, dbp ready

        if (lo) {
            // ---- P2-low: dW + W update + Wtb + staging ----
            const bf16x8 ax0 = *(const bf16x8*)&xsT[cb][16*ws + la][8*g];
            const bf16x8 ax1 = *(const bf16x8*)&xsT[cb][16*ws + la][32 + 8*g];
#pragma unroll
            for (int n = 0; n < 4; ++n) {
                bf16x8 q0 = *(const bf16x8*)&gsT[16*n + la][8*g];
                bf16x8 q1 = *(const bf16x8*)&gsT[16*n + la][32 + 8*g];
                f32x4 dw = {0.f,0.f,0.f,0.f};
                dw = __builtin_amdgcn_mfma_f32_16x16x32_bf16(ax0, q0, dw, 0,0,0);
                dw = __builtin_amdgcn_mfma_f32_16x16x32_bf16(ax1, q1, dw, 0,0,0);
                short4v sw;
#pragma unroll
                for (int i = 0; i < 4; ++i) {
                    Wreg[i][n] -= dw[i];
                    sw[i] = cvt_bf16(Wreg[i][n]);
                }
                *(short4v*)&Wtb[16*n + la][r0] = sw;
            }
            if (pf) {                       // stage chunk c+1
#pragma unroll
                for (int i4 = 0; i4 < 4; ++i4) {
                    int f = ts + 256*i4, k = f >> 4, j = f & 15;
                    short4v s4;
                    s4[0]=cvt_bf16(xl[i4].x); s4[1]=cvt_bf16(xl[i4].y);
                    s4[2]=cvt_bf16(xl[i4].z); s4[3]=cvt_bf16(xl[i4].w);
                    *(short4v*)&xs_rm[nb][k][4*j] = s4;
                }
#pragma unroll
                for (int n = 0; n < 4; ++n) {
                    short4v sv;
#pragma unroll
                    for (int i = 0; i < 4; ++i) sv[i] = cvt_bf16(xkh[i][n]);
                    *(short4v*)&xsT[nb][16*n + la][r0] = sv;
                }
            }
            if (w == 0) {                   // bias state update (wave 0 only)
                float s = dbp[0][l];
#pragma unroll
                for (int p = 1; p < 8; ++p) s += dbp[p][l];
                bs[l] -= s;
            }
        } else {
            // ---- P2-high: out = z + b_old - (Gram+1)@gs -> outb (coalesced later) ----
            const bf16x8 ar0 = *(const bf16x8*)&Gr[16*ws + la][8*g];
            const bf16x8 ar1 = *(const bf16x8*)&Gr[16*ws + la][32 + 8*g];
#pragma unroll
            for (int n = 0; n < 4; ++n) {
                bf16x8 q0 = *(const bf16x8*)&gsT[16*n + la][8*g];
                bf16x8 q1 = *(const bf16x8*)&gsT[16*n + la][32 + 8*g];
                f32x4 og = {0.f,0.f,0.f,0.f};
                og = __builtin_amdgcn_mfma_f32_16x16x32_bf16(ar0, q0, og, 0,0,0);
                og = __builtin_amdgcn_mfma_f32_16x16x32_bf16(ar1, q1, og, 0,0,0);
                f32x4 ov;
#pragma unroll
                for (int i = 0; i < 4; ++i)
                    ov[i] = zt[n][i] - og[i] + bold[n];
                *(f32x4*)&outb[16*n + la][r0] = ov;   // [e][k], k contiguous
            }
        }
        if (pf) {
#pragma unroll
            for (int ii = 0; ii < 2; ++ii)
#pragma unroll
                for (int n = 0; n < 4; ++n)
                    xvg[ii][n] = xvN[ii][n];
        }
        __syncthreads();    // C: Wtb, staged buffers, outb, bs ready
    }

    // store final chunk's output
    {
        float* ocp = ob + (NCC-1)*CSC*DC;
        const int kk = 4*w + (l >> 4);
        const int e0 = 4*(l & 15);
#pragma unroll
        for (int p = 0; p < 2; ++p) {
            int k2 = kk + 32*p;
            float4 v;
            v.x = outb[e0+0][k2]; v.y = outb[e0+1][k2];
            v.z = outb[e0+2][k2]; v.w = outb[e0+3][k2];
            *(float4*)(ocp + k2*DC + e0) = v;
        }
    }
}

extern "C" void kernel_launch(void* const* d_in, const int* in_sizes, int n_in,
                              void* d_out, int out_size, void* d_ws, size_t ws_size,
                              hipStream_t stream) {
    const float* xk         = (const float*)d_in[0];
    const float* xv         = (const float*)d_in[1];
    const float* weight     = (const float*)d_in[2];
    const float* bias       = (const float*)d_in[3];
    const float* gamma      = (const float*)d_in[4];
    const float* beta       = (const float*)d_in[5];
    const float* theta      = (const float*)d_in[6];
    const float* theta_bias = (const float*)d_in[7];
    const float* alpha      = (const float*)d_in[8];
    float* out = (float*)d_out;

    (void)hipFuncSetAttribute((const void*)ttt_kernel,
                              hipFuncAttributeMaxDynamicSharedMemorySize,
                              LDS_BYTES);
    ttt_kernel<<<64, 512, LDS_BYTES, stream>>>(xk, xv, weight, bias, gamma, beta,
                                               theta, theta_bias, alpha, out);
}

// Round 12
// 178.564 us; speedup vs baseline: 1.0065x; 1.0065x over previous
//
#include <hip/hip_runtime.h>
#include <hip/hip_bf16.h>
#include <math.h>

#define NCC 64
#define CSC 64
#define DC 64
#define S 72            // bf16 LDS row stride (144 B rows)
#define SZ 68           // zp fp32 row stride
#define EPSF 1e-6f
#define LDS_BYTES 120832

typedef __attribute__((ext_vector_type(8)))  short bf16x8;
typedef __attribute__((ext_vector_type(4)))  float f32x4;
typedef __attribute__((ext_vector_type(16))) float f32x16;
typedef __attribute__((ext_vector_type(4)))  short short4v;
typedef __attribute__((ext_vector_type(8)))  short short8v;

static __device__ __forceinline__ short cvt_bf16(float x) { // HW RNE
    union { __hip_bfloat16 b; short s; } u;
    u.b = __float2bfloat16(x);
    return u.s;
}
static __device__ __forceinline__ float bf16_to_f(unsigned short hw) {
    union { unsigned u; float f; } v; v.u = ((unsigned)hw) << 16;
    return v.f;
}

// 16-lane sum via DPP row rotations (VALU-only).
#define DPP_ROR_ADD(v, N)                                                     \
    do {                                                                      \
        union { float f; int i; } _u, _r;                                     \
        _u.f = (v);                                                           \
        _r.i = __builtin_amdgcn_mov_dpp(_u.i, 0x120 + (N), 0xF, 0xF, true);   \
        (v) += _r.f;                                                          \
    } while (0)

static __device__ __forceinline__ float red16(float v) {
    DPP_ROR_ADD(v, 1);
    DPP_ROR_ADD(v, 2);
    DPP_ROR_ADD(v, 4);
    DPP_ROR_ADD(v, 8);
    return v;
}

#define MFMA16 __builtin_amdgcn_mfma_f32_16x16x32_bf16
#define MFMA32 __builtin_amdgcn_mfma_f32_32x32x16_bf16

__global__ __launch_bounds__(512, 1) void ttt_kernel(
    const float* __restrict__ xk, const float* __restrict__ xv,
    const float* __restrict__ weight, const float* __restrict__ bias,
    const float* __restrict__ gamma, const float* __restrict__ beta,
    const float* __restrict__ theta, const float* __restrict__ theta_bias,
    const float* __restrict__ alpha, float* __restrict__ out)
{
    extern __shared__ char sb[];
    auto xs_rm = (short (*)[CSC][S])(sb);              // [2][64][S] xk row-major [k][d]
    auto xsT   = (short (*)[DC][S]) (sb + 18432);      // [3][64][S] xk^T [d][k]
    auto gsT   = (short (*)[DC][S]) (sb + 46080);      // [2][64][S] gs^T [e][k]
    auto Gr    = (short (*)[DC][S]) (sb + 64512);      // [2][64][S] -(Gram+1) [j'][j]
    auto Cx    = (short (*)[S])     (sb + 82944);      // [64][S] -(Cross+1) [k'][k]
    auto Wtb   = (short (*)[S])     (sb + 92160);      // [64][S] W [e][d]
    auto zpb   = (float (*)[SZ])    (sb + 101376);     // [64][SZ] zp+b [e][k']
    auto dbp   = (float (*)[4][DC]) (sb + 118784);     // [2][4][64] db partials

    const int t    = threadIdx.x;
    const int w    = t >> 6;
    const bool crit = (w < 4);         // critical: corr+epilogue+out
    const int ws   = w & 3;
    const int l    = t & 63;
    const int g    = l >> 4, la = l & 15;     // 16-style
    const int la5  = l & 31, h5 = l >> 5;     // 32-style
    const int R    = ws >> 1, E = ws & 1;     // side 32x32 tile coords
    const int r0   = 16*ws + 4*g;
    const int ts   = 64*ws + l;               // side staging id 0..255
    const int bh   = blockIdx.x;
    const int h    = bh & 15;

    const size_t bh_off = (size_t)bh * NCC*CSC*DC;
    const float* xkb = xk + bh_off;
    const float* xvb = xv + bh_off;
    float*       ob  = out + bh_off;

    // role state
    float gam[4], bet[4], thv[4], tok[4], tb = 0.f;
    float xvg[4][4], xvN[4][4];
    float Wreg[16];                  // side: W state (32x32 C-frag layout)
    float bcolh = 0.f;               // side: bias state at e = 32E+la5
    float4 xl[4];                    // side: rm-staging prefetch regs
    float xkh[4][4];                 // side: xsT-staging prefetch regs

    if (crit) {
#pragma unroll
        for (int n = 0; n < 4; ++n) {
            gam[n] = gamma[h*DC + 16*n + la];
            bet[n] = beta [h*DC + 16*n + la];
            thv[n] = theta[h*DC + 16*n + la];
        }
        tb = theta_bias[h];
#pragma unroll
        for (int i = 0; i < 4; ++i)
            tok[i] = fmaxf(1.0f/(float)(r0+i+1) + alpha[r0+i], 0.0f);
#pragma unroll
        for (int i = 0; i < 4; ++i)
#pragma unroll
            for (int n = 0; n < 4; ++n)
                xvg[i][n] = xvb[(r0+i)*DC + 16*n + la];
    } else {
        // issue chunk-0 xk loads
#pragma unroll
        for (int j = 0; j < 4; ++j) xl[j] = ((const float4*)xkb)[ts + 256*j];
#pragma unroll
        for (int i = 0; i < 4; ++i)
#pragma unroll
            for (int n = 0; n < 4; ++n)
                xkh[i][n] = xkb[(r0+i)*DC + 16*n + la];
        bcolh = bias[h*DC + 32*E + la5];
        const float* wg = weight + h*DC*DC;
#pragma unroll
        for (int q = 0; q < 4; ++q) {
            short4v sw;
#pragma unroll
            for (int j = 0; j < 4; ++j) {
                Wreg[4*q+j] = wg[(32*R + 8*q + 4*h5 + j)*DC + 32*E + la5];
                sw[j] = cvt_bf16(Wreg[4*q+j]);
            }
            *(short4v*)&Wtb[32*E + la5][32*R + 8*q + 4*h5] = sw;
        }
        // stage chunk 0
#pragma unroll
        for (int j4 = 0; j4 < 4; ++j4) {
            int f = ts + 256*j4, k = f >> 4, jj = f & 15;
            short4v s4;
            s4[0]=cvt_bf16(xl[j4].x); s4[1]=cvt_bf16(xl[j4].y);
            s4[2]=cvt_bf16(xl[j4].z); s4[3]=cvt_bf16(xl[j4].w);
            *(short4v*)&xs_rm[0][k][4*jj] = s4;
        }
#pragma unroll
        for (int n = 0; n < 4; ++n) {
            short4v sv;
#pragma unroll
            for (int i = 0; i < 4; ++i) sv[i] = cvt_bf16(xkh[i][n]);
            *(short4v*)&xsT[0][16*n + la][r0] = sv;
        }
    }
    if (t < 64) {   // zero Cx AND gsT[1]: at c=0 the corr MFMA reads both;
                    // uninitialized bf16 can decode Inf/NaN and 0*Inf = NaN.
        short8v z8 = {0,0,0,0,0,0,0,0};
#pragma unroll
        for (int j = 0; j < 9; ++j) {
            *(short8v*)&Cx[t][8*j]        = z8;
            *(short8v*)&gsT[1][t][8*j]    = z8;
        }
    }
    __syncthreads();

    if (!crit) {                     // zp(0) = xs0@W0 + b0
        bf16x8 az0[4], bz0[4];
#pragma unroll
        for (int s = 0; s < 4; ++s) {
            az0[s] = *(const bf16x8*)&xs_rm[0][32*R + la5][16*s + 8*h5];
            bz0[s] = *(const bf16x8*)&Wtb[32*E + la5][16*s + 8*h5];
        }
        f32x16 zz = {0.f,0.f,0.f,0.f,0.f,0.f,0.f,0.f,
                     0.f,0.f,0.f,0.f,0.f,0.f,0.f,0.f};
#pragma unroll
        for (int s = 0; s < 4; ++s) zz = MFMA32(az0[s], bz0[s], zz, 0,0,0);
#pragma unroll
        for (int q = 0; q < 4; ++q) {
            f32x4 zv;
#pragma unroll
            for (int j = 0; j < 4; ++j) zv[j] = zz[4*q+j] + bcolh;
            *(f32x4*)&zpb[32*E + la5][32*R + 8*q + 4*h5] = zv;
        }
        // issue chunk-1 loads
        const float* xk1 = xkb + CSC*DC;
#pragma unroll
        for (int j = 0; j < 4; ++j) xl[j] = ((const float4*)xk1)[ts + 256*j];
#pragma unroll
        for (int i = 0; i < 4; ++i)
#pragma unroll
            for (int n = 0; n < 4; ++n)
                xkh[i][n] = xk1[(r0+i)*DC + 16*n + la];
    }
    __syncthreads();

    for (int c = 0; c < NCC; ++c) {
        const int cb = c & 1, nb = cb ^ 1;
        const int cp3 = c % 3, cn3 = (c+1) % 3, co3 = (c+2) % 3; // co3 == (c-1)%3
        const bool pf1 = (c + 1 < NCC), pf2 = (c + 2 < NCC);

        f32x4 zt[4];                 // critical: z(c) C-frags (live across B')
        bf16x8 az[4];                // side: xs_rm(c) A-frags (live across B')

        if (crit) {
            // issue xv(c+1) loads first (consumed next iteration)
            if (pf1) {
                const float* xvn = xvb + (c+1)*CSC*DC;
#pragma unroll
                for (int i = 0; i < 4; ++i)
#pragma unroll
                    for (int n = 0; n < 4; ++n)
                        xvN[i][n] = xvn[(r0+i)*DC + 16*n + la];
            }
            // ---- z(c) = zp(c) + Cxneg @ gs(c-1) ----
#pragma unroll
            for (int n = 0; n < 4; ++n)
                zt[n] = *(const f32x4*)&zpb[16*n + la][r0];
            const bf16x8 cx0 = *(const bf16x8*)&Cx[16*ws + la][8*g];
            const bf16x8 cx1 = *(const bf16x8*)&Cx[16*ws + la][32 + 8*g];
#pragma unroll
            for (int n = 0; n < 4; ++n) {
                bf16x8 q0 = *(const bf16x8*)&gsT[nb][16*n + la][8*g];
                bf16x8 q1 = *(const bf16x8*)&gsT[nb][16*n + la][32 + 8*g];
                zt[n] = MFMA16(cx0, q0, zt[n], 0,0,0);
                zt[n] = MFMA16(cx1, q1, zt[n], 0,0,0);
            }
            // epilogue xk from xsT(c)
            float xkE[4][4];
#pragma unroll
            for (int n = 0; n < 4; ++n) {
                short4v pk = *(const short4v*)&xsT[cp3][16*n + la][r0];
#pragma unroll
                for (int i = 0; i < 4; ++i)
                    xkE[i][n] = bf16_to_f((unsigned short)pk[i]);
            }
            // ---- epilogue: 4 rows/thread (z complete incl. bias) ----
            float gsv[4][4];
#pragma unroll
            for (int i = 0; i < 4; ++i) {
                float z0 = zt[0][i], z1 = zt[1][i], z2 = zt[2][i], z3 = zt[3][i];
                float szz = red16(z0*z0 + z1*z1 + z2*z2 + z3*z3);
                float sz  = red16(z0 + z1 + z2 + z3);
                float thd = red16(xkE[i][0]*thv[0] + xkE[i][1]*thv[1] +
                                  xkE[i][2]*thv[2] + xkE[i][3]*thv[3]);
                float mu   = sz * (1.0f/DC);
                float var  = szz*(1.0f/DC) - mu*mu;
                float rstd = rsqrtf(var + EPSF);
                float ex   = __expf(-(thd + tb));
                float lr   = __builtin_amdgcn_rcpf(1.0f + ex);
                float eta  = tok[i]*lr*(1.0f/DC);
                float zz4[4] = {z0,z1,z2,z3};
                float xh[4], gxh[4], a1v = 0.f, a2v = 0.f;
#pragma unroll
                for (int n = 0; n < 4; ++n) {
                    xh[n] = (zz4[n]-mu)*rstd;
                    float y  = fmaf(gam[n], xh[n], bet[n]);
                    float go = y - xvg[i][n] + xkE[i][n];
                    gxh[n] = go*gam[n];
                    a1v += gxh[n];
                    a2v = fmaf(gxh[n], xh[n], a2v);
                }
                float s1 = red16(a1v), s2 = red16(a2v);
                float sc = rstd*(1.0f/DC)*eta;
#pragma unroll
                for (int n = 0; n < 4; ++n)
                    gsv[i][n] = (64.f*gxh[n] - s1 - xh[n]*s2)*sc;
            }
#pragma unroll
            for (int n = 0; n < 4; ++n) {
                short4v sg;
#pragma unroll
                for (int i = 0; i < 4; ++i) sg[i] = cvt_bf16(gsv[i][n]);
                *(short4v*)&gsT[cb][16*n + la][r0] = sg;
            }
            float dbl[4];
#pragma unroll
            for (int n = 0; n < 4; ++n) {
                float dd = gsv[0][n]+gsv[1][n]+gsv[2][n]+gsv[3][n];
                dd += __shfl_xor(dd, 16);
                dd += __shfl_xor(dd, 32);
                dbl[n] = dd;
            }
            if (l < 16) {
                f32x4 dv = {dbl[0], dbl[1], dbl[2], dbl[3]};
                *(f32x4*)&dbp[cb][ws][4*la] = dv;
            }
        } else {
            // ---- side pre-B': dW(c-1) + W/bias update + Gram(c) + staging ----
            if (c > 0) {
                bf16x8 ax[4], bx[4];
#pragma unroll
                for (int s = 0; s < 4; ++s) {
                    ax[s] = *(const bf16x8*)&xsT[co3][32*R + la5][16*s + 8*h5];
                    bx[s] = *(const bf16x8*)&gsT[nb][32*E + la5][16*s + 8*h5];
                }
                f32x16 dw = {0.f,0.f,0.f,0.f,0.f,0.f,0.f,0.f,
                             0.f,0.f,0.f,0.f,0.f,0.f,0.f,0.f};
#pragma unroll
                for (int s = 0; s < 4; ++s) dw = MFMA32(ax[s], bx[s], dw, 0,0,0);
#pragma unroll
                for (int q = 0; q < 4; ++q) {
                    short4v sw;
#pragma unroll
                    for (int j = 0; j < 4; ++j) {
                        Wreg[4*q+j] -= dw[4*q+j];
                        sw[j] = cvt_bf16(Wreg[4*q+j]);
                    }
                    *(short4v*)&Wtb[32*E + la5][32*R + 8*q + 4*h5] = sw;
                }
                int idx = 4*(la5 & 15) + 2*E + (la5 >> 4);
                bcolh -= dbp[nb][0][idx] + dbp[nb][1][idx] +
                         dbp[nb][2][idx] + dbp[nb][3][idx];
            }
            // Gram(c)+1, negated
#pragma unroll
            for (int s = 0; s < 4; ++s)
                az[s] = *(const bf16x8*)&xs_rm[cb][32*R + la5][16*s + 8*h5];
            bf16x8 bg[4];
            if (R == E) {
#pragma unroll
                for (int s = 0; s < 4; ++s) bg[s] = az[s];
            } else {
#pragma unroll
                for (int s = 0; s < 4; ++s)
                    bg[s] = *(const bf16x8*)&xs_rm[cb][32*E + la5][16*s + 8*h5];
            }
            f32x16 gg = {0.f,0.f,0.f,0.f,0.f,0.f,0.f,0.f,
                         0.f,0.f,0.f,0.f,0.f,0.f,0.f,0.f};
#pragma unroll
            for (int s = 0; s < 4; ++s) gg = MFMA32(az[s], bg[s], gg, 0,0,0);
#pragma unroll
            for (int q = 0; q < 4; ++q) {
                short4v sg;
#pragma unroll
                for (int j = 0; j < 4; ++j) sg[j] = cvt_bf16(-(gg[4*q+j] + 1.0f));
                *(short4v*)&Gr[cb][32*E + la5][32*R + 8*q + 4*h5] = sg;
            }
            // stage chunk c+1 (prefetched regs)
            if (pf1) {
#pragma unroll
                for (int j4 = 0; j4 < 4; ++j4) {
                    int f = ts + 256*j4, k = f >> 4, jj = f & 15;
                    short4v s4;
                    s4[0]=cvt_bf16(xl[j4].x); s4[1]=cvt_bf16(xl[j4].y);
                    s4[2]=cvt_bf16(xl[j4].z); s4[3]=cvt_bf16(xl[j4].w);
                    *(short4v*)&xs_rm[nb][k][4*jj] = s4;
                }
#pragma unroll
                for (int n = 0; n < 4; ++n) {
                    short4v sv;
#pragma unroll
                    for (int i = 0; i < 4; ++i) sv[i] = cvt_bf16(xkh[i][n]);
                    *(short4v*)&xsT[cn3][16*n + la][r0] = sv;
                }
            }
        }
        __syncthreads();    // B': gsT(c), Gr(c), dbp(c), staged(c+1) ready

        if (crit) {
            // ---- out(c) = z(c) + Grneg @ gs(c) ----
            const bf16x8 ag0 = *(const bf16x8*)&Gr[cb][16*ws + la][8*g];
            const bf16x8 ag1 = *(const bf16x8*)&Gr[cb][16*ws + la][32 + 8*g];
            float* oc = ob + c*CSC*DC;
#pragma unroll
            for (int n = 0; n < 4; ++n) {
                bf16x8 q0 = *(const bf16x8*)&gsT[cb][16*n + la][8*g];
                bf16x8 q1 = *(const bf16x8*)&gsT[cb][16*n + la][32 + 8*g];
                f32x4 og = zt[n];
                og = MFMA16(ag0, q0, og, 0,0,0);
                og = MFMA16(ag1, q1, og, 0,0,0);
#pragma unroll
                for (int i = 0; i < 4; ++i)
                    oc[(r0+i)*DC + 16*n + la] = og[i];
            }
            if (pf1) {
#pragma unroll
                for (int i = 0; i < 4; ++i)
#pragma unroll
                    for (int n = 0; n < 4; ++n)
                        xvg[i][n] = xvN[i][n];
            }
        } else {
            // issue chunk c+2 loads
            if (pf2) {
                const float* xk2 = xkb + (c+2)*CSC*DC;
#pragma unroll
                for (int j = 0; j < 4; ++j) xl[j] = ((const float4*)xk2)[ts + 256*j];
#pragma unroll
                for (int i = 0; i < 4; ++i)
#pragma unroll
                    for (int n = 0; n < 4; ++n)
                        xkh[i][n] = xk2[(r0+i)*DC + 16*n + la];
            }
            if (pf1) {
                // zp(c+1) = xs(c+1)@W_c + b_c
                bf16x8 an[4], bw[4];
#pragma unroll
                for (int s = 0; s < 4; ++s) {
                    an[s] = *(const bf16x8*)&xs_rm[nb][32*R + la5][16*s + 8*h5];
                    bw[s] = *(const bf16x8*)&Wtb[32*E + la5][16*s + 8*h5];
                }
                f32x16 zz = {0.f,0.f,0.f,0.f,0.f,0.f,0.f,0.f,
                             0.f,0.f,0.f,0.f,0.f,0.f,0.f,0.f};
#pragma unroll
                for (int s = 0; s < 4; ++s) zz = MFMA32(an[s], bw[s], zz, 0,0,0);
#pragma unroll
                for (int q = 0; q < 4; ++q) {
                    f32x4 zv;
#pragma unroll
                    for (int j = 0; j < 4; ++j) zv[j] = zz[4*q+j] + bcolh;
                    *(f32x4*)&zpb[32*E + la5][32*R + 8*q + 4*h5] = zv;
                }
                // Cx(c+1,c)+1, negated: A = xs(c) (az regs), B = xs(c+1)
                bf16x8 bn[4];
#pragma unroll
                for (int s = 0; s < 4; ++s)
                    bn[s] = *(const bf16x8*)&xs_rm[nb][32*E + la5][16*s + 8*h5];
                f32x16 xx = {0.f,0.f,0.f,0.f,0.f,0.f,0.f,0.f,
                             0.f,0.f,0.f,0.f,0.f,0.f,0.f,0.f};
#pragma unroll
                for (int s = 0; s < 4; ++s) xx = MFMA32(az[s], bn[s], xx, 0,0,0);
#pragma unroll
                for (int q = 0; q < 4; ++q) {
                    short4v sx;
#pragma unroll
                    for (int j = 0; j < 4; ++j) sx[j] = cvt_bf16(-(xx[4*q+j] + 1.0f));
                    *(short4v*)&Cx[32*E + la5][32*R + 8*q + 4*h5] = sx;
                }
            }
        }
        __syncthreads();    // C: zp(c+1), Cx(c+1), Wtb(W_c) consumed-ordering
    }
}

extern "C" void kernel_launch(void* const* d_in, const int* in_sizes, int n_in,
                              void* d_out, int out_size, void* d_ws, size_t ws_size,
                              hipStream_t stream) {
    const float* xk         = (const float*)d_in[0];
    const float* xv         = (const float*)d_in[1];
    const float* weight     = (const float*)d_in[2];
    const float* bias       = (const float*)d_in[3];
    const float* gamma      = (const float*)d_in[4];
    const float* beta       = (const float*)d_in[5];
    const float* theta      = (const float*)d_in[6];
    const float* theta_bias = (const float*)d_in[7];
    const float* alpha      = (const float*)d_in[8];
    float* out = (float*)d_out;

    (void)hipFuncSetAttribute((const void*)ttt_kernel,
                              hipFuncAttributeMaxDynamicSharedMemorySize,
                              LDS_BYTES);
    ttt_kernel<<<64, 512, LDS_BYTES, stream>>>(xk, xv, weight, bias, gamma, beta,
                                               theta, theta_bias, alpha, out);
}

// Round 13
// 141.159 us; speedup vs baseline: 1.2732x; 1.2650x over previous
//
#include <hip/hip_runtime.h>
#include <hip/hip_bf16.h>
#include <math.h>

#define NCC 64
#define CSC 64
#define DC 64
#define S 72            // bf16 LDS row stride (144 B rows)
#define EPSF 1e-6f
#define LDS_BYTES 66816

typedef __attribute__((ext_vector_type(8))) short bf16x8;   // MFMA A/B frag
typedef __attribute__((ext_vector_type(4))) float f32x4;    // MFMA C/D frag
typedef __attribute__((ext_vector_type(4))) short short4v;
typedef __attribute__((ext_vector_type(2))) short short2v;

static __device__ __forceinline__ short cvt_bf16(float x) { // HW RNE
    union { __hip_bfloat16 b; short s; } u;
    u.b = __float2bfloat16(x);
    return u.s;
}
static __device__ __forceinline__ float bf16_to_f(unsigned hw) {
    union { unsigned u; float f; } v; v.u = hw << 16;
    return v.f;
}

// 16-lane sum via DPP row rotations (VALU-only; DPP row = 16 lanes).
#define DPP_ROR_ADD(v, N)                                                     \
    do {                                                                      \
        union { float f; int i; } _u, _r;                                     \
        _u.f = (v);                                                           \
        _r.i = __builtin_amdgcn_mov_dpp(_u.i, 0x120 + (N), 0xF, 0xF, true);   \
        (v) += _r.f;                                                          \
    } while (0)

static __device__ __forceinline__ float red16(float v) {
    DPP_ROR_ADD(v, 1);
    DPP_ROR_ADD(v, 2);
    DPP_ROR_ADD(v, 4);
    DPP_ROR_ADD(v, 8);
    return v;
}

__global__ __launch_bounds__(512, 1) void ttt_kernel(
    const float* __restrict__ xk, const float* __restrict__ xv,
    const float* __restrict__ weight, const float* __restrict__ bias,
    const float* __restrict__ gamma, const float* __restrict__ beta,
    const float* __restrict__ theta, const float* __restrict__ theta_bias,
    const float* __restrict__ alpha, float* __restrict__ out)
{
    extern __shared__ char sb[];
    auto xs_rm = (short (*)[CSC][S])(sb);             // [2][64][S] xk row-major
    auto xsT   = (short (*)[DC][S]) (sb + 18432);     // [2][64][S] xk^T (A of dW, epi xk)
    auto gsT   = (short (*)[S])     (sb + 36864);     // gs^T (B of dW and out)
    auto Gr    = (short (*)[S])     (sb + 46080);     // -(Gram+1) (ones-trick)
    auto Wtb   = (short (*)[S])     (sb + 55296);     // W [e][d] (B of z)
    auto dbp   = (float (*)[DC])    (sb + 64512);     // [8][64] db partials
    auto bs    = (float*)           (sb + 66560);     // [64] bias state, bs[4*la+n]=b[16n+la]

    const int t   = threadIdx.x;
    const int w   = t >> 6;           // wave 0..7
    const bool lo = (w < 4);          // state half vs output half
    const int ws  = w & 3;            // band within half
    const int l   = t & 63;
    const int g   = l >> 4, la = l & 15;
    const int r0  = 16*ws + 4*g;      // first row of this thread's C-frag
    const int io  = lo ? 0 : 2;       // epilogue row pair offset
    const int ts  = 64*ws + l;        // per-half thread id 0..255
    const int bh  = blockIdx.x;       // 0..63
    const int h   = bh & 15;

    const size_t bh_off = (size_t)bh * NCC*CSC*DC;
    const float* xkb = xk + bh_off;
    const float* xvb = xv + bh_off;
    float*       ob  = out + bh_off;

    // constants (both halves)
    float gam[4], bet[4], thv[4];
#pragma unroll
    for (int n = 0; n < 4; ++n) {
        gam[n] = gamma[h*DC + 16*n + la];
        bet[n] = beta [h*DC + 16*n + la];
        thv[n] = theta[h*DC + 16*n + la];
    }
    const float tb = theta_bias[h];
    float tokk[2];
#pragma unroll
    for (int ii = 0; ii < 2; ++ii) {
        int r = r0 + io + ii;
        tokk[ii] = fmaxf(1.0f/(float)(r+1) + alpha[r], 0.0f);
    }
    // bias state: bs[4*la'+n'] = bias[16n'+la']
    if (t < DC) bs[t] = bias[h*DC + 16*(t & 3) + (t >> 2)];

    float Wreg[4][4];                 // low half: W state
    float4 xl[4];                     // low half: rm staging regs
    float xkh[4][4];                  // low half: xsT staging rows
    float xvg[2][4];                  // epilogue xv rows (both halves)

#pragma unroll
    for (int ii = 0; ii < 2; ++ii)
#pragma unroll
        for (int n = 0; n < 4; ++n)
            xvg[ii][n] = xvb[(r0+io+ii)*DC + 16*n + la];

    if (lo) {
        const float* wg = weight + h*DC*DC;
#pragma unroll
        for (int i = 0; i < 4; ++i)
#pragma unroll
            for (int n = 0; n < 4; ++n)
                Wreg[i][n] = wg[(r0+i)*DC + 16*n + la];
#pragma unroll
        for (int n = 0; n < 4; ++n) {
            short4v sv;
#pragma unroll
            for (int i = 0; i < 4; ++i) sv[i] = cvt_bf16(Wreg[i][n]);
            *(short4v*)&Wtb[16*n + la][r0] = sv;
        }
#pragma unroll
        for (int i4 = 0; i4 < 4; ++i4) xl[i4] = ((const float4*)xkb)[ts + 256*i4];
#pragma unroll
        for (int i = 0; i < 4; ++i)
#pragma unroll
            for (int n = 0; n < 4; ++n)
                xkh[i][n] = xkb[(r0+i)*DC + 16*n + la];
#pragma unroll
        for (int i4 = 0; i4 < 4; ++i4) {    // stage chunk 0 row-major
            int f = ts + 256*i4, k = f >> 4, j = f & 15;
            short4v s4;
            s4[0]=cvt_bf16(xl[i4].x); s4[1]=cvt_bf16(xl[i4].y);
            s4[2]=cvt_bf16(xl[i4].z); s4[3]=cvt_bf16(xl[i4].w);
            *(short4v*)&xs_rm[0][k][4*j] = s4;
        }
#pragma unroll
        for (int n = 0; n < 4; ++n) {       // stage chunk 0 transposed
            short4v sv;
#pragma unroll
            for (int i = 0; i < 4; ++i) sv[i] = cvt_bf16(xkh[i][n]);
            *(short4v*)&xsT[0][16*n + la][r0] = sv;
        }
    }
    __syncthreads();

    for (int c = 0; c < NCC; ++c) {
        const int cb = c & 1, nb = cb ^ 1;
        const bool pf = (c + 1 < NCC);

        // b_old for this chunk (DS latency hidden under z MFMAs)
        f32x4 bold = *(const f32x4*)&bs[4*la];

        // ---- P1: z = xs@W (all waves) ----
        const bf16x8 a0 = *(const bf16x8*)&xs_rm[cb][16*ws + la][8*g];
        const bf16x8 a1 = *(const bf16x8*)&xs_rm[cb][16*ws + la][32 + 8*g];
        f32x4 zt[4];
#pragma unroll
        for (int n = 0; n < 4; ++n) {
            bf16x8 w0 = *(const bf16x8*)&Wtb[16*n + la][8*g];
            bf16x8 w1 = *(const bf16x8*)&Wtb[16*n + la][32 + 8*g];
            f32x4 zz = {0.f,0.f,0.f,0.f};
            zz = __builtin_amdgcn_mfma_f32_16x16x32_bf16(a0, w0, zz, 0,0,0);
            zz = __builtin_amdgcn_mfma_f32_16x16x32_bf16(a1, w1, zz, 0,0,0);
            zt[n] = zz;
        }
        if (!lo) {                    // -(Gram+1) (ones-trick) on high half
#pragma unroll
            for (int n = 0; n < 4; ++n) {
                bf16x8 b0 = *(const bf16x8*)&xs_rm[cb][16*n + la][8*g];
                bf16x8 b1 = *(const bf16x8*)&xs_rm[cb][16*n + la][32 + 8*g];
                f32x4 cc = {0.f,0.f,0.f,0.f};
                cc = __builtin_amdgcn_mfma_f32_16x16x32_bf16(a0, b0, cc, 0,0,0);
                cc = __builtin_amdgcn_mfma_f32_16x16x32_bf16(a1, b1, cc, 0,0,0);
                short4v sg;
#pragma unroll
                for (int i = 0; i < 4; ++i) sg[i] = cvt_bf16(-(cc[i] + 1.0f));
                *(short4v*)&Gr[16*n + la][r0] = sg;
            }
        }

        // epilogue xk rows from xsT (b32, conflict-free)
        float xkq[2][4];
#pragma unroll
        for (int n = 0; n < 4; ++n) {
            unsigned pk = *(const unsigned*)&xsT[cb][16*n + la][r0 + io];
            xkq[0][n] = bf16_to_f(pk & 0xFFFFu);
            xkq[1][n] = bf16_to_f(pk >> 16);
        }

        // VMEM prefetch for chunk c+1 (latency spans epilogue + barrier)
        float xvN[2][4];
        if (pf) {
            const float* xvn = xvb + (c+1)*CSC*DC;
#pragma unroll
            for (int ii = 0; ii < 2; ++ii)
#pragma unroll
                for (int n = 0; n < 4; ++n)
                    xvN[ii][n] = xvn[(r0+io+ii)*DC + 16*n + la];
            if (lo) {
                const float* xkn = xkb + (c+1)*CSC*DC;
#pragma unroll
                for (int i4 = 0; i4 < 4; ++i4) xl[i4] = ((const float4*)xkn)[ts + 256*i4];
#pragma unroll
                for (int i = 0; i < 4; ++i)
#pragma unroll
                    for (int n = 0; n < 4; ++n)
                        xkh[i][n] = xkn[(r0+i)*DC + 16*n + la];
            }
        }

        // select this half's 2 epilogue rows
        float zrow[2][4];
        if (lo) {
#pragma unroll
            for (int n = 0; n < 4; ++n) { zrow[0][n] = zt[n][0]; zrow[1][n] = zt[n][1]; }
        } else {
#pragma unroll
            for (int n = 0; n < 4; ++n) { zrow[0][n] = zt[n][2]; zrow[1][n] = zt[n][3]; }
        }

        // ---- epilogue: 2 rows/thread, all 8 waves ----
        float gsv[2][4];
#pragma unroll
        for (int ii = 0; ii < 2; ++ii) {
            float z4[4];
#pragma unroll
            for (int n = 0; n < 4; ++n) z4[n] = zrow[ii][n] + bold[n];
            float szz = red16(z4[0]*z4[0] + z4[1]*z4[1] + z4[2]*z4[2] + z4[3]*z4[3]);
            float sz  = red16(z4[0] + z4[1] + z4[2] + z4[3]);
            float thd = red16(xkq[ii][0]*thv[0] + xkq[ii][1]*thv[1] +
                              xkq[ii][2]*thv[2] + xkq[ii][3]*thv[3]);
            float mu   = sz * (1.0f/DC);
            float var  = szz*(1.0f/DC) - mu*mu;
            float rstd = rsqrtf(var + EPSF);
            float ex   = __expf(-(thd + tb));
            float lr   = __builtin_amdgcn_rcpf(1.0f + ex);
            float eta  = tokk[ii]*lr*(1.0f/DC);
            float xh[4], gxh[4], a1v = 0.f, a2v = 0.f;
#pragma unroll
            for (int n = 0; n < 4; ++n) {
                xh[n] = (z4[n]-mu)*rstd;
                float y  = fmaf(gam[n], xh[n], bet[n]);
                float go = y - xvg[ii][n] + xkq[ii][n];
                gxh[n] = go*gam[n];
                a1v += gxh[n];
                a2v = fmaf(gxh[n], xh[n], a2v);
            }
            float s1 = red16(a1v), s2 = red16(a2v);
            float sc = rstd*(1.0f/DC)*eta;
#pragma unroll
            for (int n = 0; n < 4; ++n)
                gsv[ii][n] = (64.f*gxh[n] - s1 - xh[n]*s2)*sc;
        }
#pragma unroll
        for (int n = 0; n < 4; ++n) {       // gsT b32 pack (2 rows)
            short2v sg;
            sg[0] = cvt_bf16(gsv[0][n]);
            sg[1] = cvt_bf16(gsv[1][n]);
            *(short2v*)&gsT[16*n + la][r0 + io] = sg;
        }
        float dbl[4];
#pragma unroll
        for (int n = 0; n < 4; ++n) {       // per-wave db partial
            float dd = gsv[0][n] + gsv[1][n];
            dd += __shfl_xor(dd, 16);
            dd += __shfl_xor(dd, 32);
            dbl[n] = dd;
        }
        if (l < 16) {
            f32x4 dv = {dbl[0], dbl[1], dbl[2], dbl[3]};
            *(f32x4*)&dbp[w][4*la] = dv;
        }
        __syncthreads();    // B: gsT, Gr, dbp ready

        if (lo) {
            // ---- P2-low: dW + W update + Wtb + staging + bias (w0) ----
            const bf16x8 ax0 = *(const bf16x8*)&xsT[cb][16*ws + la][8*g];
            const bf16x8 ax1 = *(const bf16x8*)&xsT[cb][16*ws + la][32 + 8*g];
#pragma unroll
            for (int n = 0; n < 4; ++n) {
                bf16x8 q0 = *(const bf16x8*)&gsT[16*n + la][8*g];
                bf16x8 q1 = *(const bf16x8*)&gsT[16*n + la][32 + 8*g];
                f32x4 dw = {0.f,0.f,0.f,0.f};
                dw = __builtin_amdgcn_mfma_f32_16x16x32_bf16(ax0, q0, dw, 0,0,0);
                dw = __builtin_amdgcn_mfma_f32_16x16x32_bf16(ax1, q1, dw, 0,0,0);
                short4v sw;
#pragma unroll
                for (int i = 0; i < 4; ++i) {
                    Wreg[i][n] -= dw[i];
                    sw[i] = cvt_bf16(Wreg[i][n]);
                }
                *(short4v*)&Wtb[16*n + la][r0] = sw;
            }
            if (pf) {                       // stage chunk c+1
#pragma unroll
                for (int i4 = 0; i4 < 4; ++i4) {
                    int f = ts + 256*i4, k = f >> 4, j = f & 15;
                    short4v s4;
                    s4[0]=cvt_bf16(xl[i4].x); s4[1]=cvt_bf16(xl[i4].y);
                    s4[2]=cvt_bf16(xl[i4].z); s4[3]=cvt_bf16(xl[i4].w);
                    *(short4v*)&xs_rm[nb][k][4*j] = s4;
                }
#pragma unroll
                for (int n = 0; n < 4; ++n) {
                    short4v sv;
#pragma unroll
                    for (int i = 0; i < 4; ++i) sv[i] = cvt_bf16(xkh[i][n]);
                    *(short4v*)&xsT[nb][16*n + la][r0] = sv;
                }
            }
            if (w == 0) {                   // bias state update (wave 0 only)
                float s = dbp[0][l];
#pragma unroll
                for (int p = 1; p < 8; ++p) s += dbp[p][l];
                bs[l] -= s;
            }
        } else {
            // ---- P2-high: out = z + (-(G+1))@gs + b_old (acc into zt) ----
            const bf16x8 ar0 = *(const bf16x8*)&Gr[16*ws + la][8*g];
            const bf16x8 ar1 = *(const bf16x8*)&Gr[16*ws + la][32 + 8*g];
            float* oc = ob + c*CSC*DC;
#pragma unroll
            for (int n = 0; n < 4; ++n) {
                bf16x8 q0 = *(const bf16x8*)&gsT[16*n + la][8*g];
                bf16x8 q1 = *(const bf16x8*)&gsT[16*n + la][32 + 8*g];
                f32x4 og = zt[n];
                og = __builtin_amdgcn_mfma_f32_16x16x32_bf16(ar0, q0, og, 0,0,0);
                og = __builtin_amdgcn_mfma_f32_16x16x32_bf16(ar1, q1, og, 0,0,0);
#pragma unroll
                for (int i = 0; i < 4; ++i)
                    oc[(r0+i)*DC + 16*n + la] = og[i] + bold[n];
            }
        }
        if (pf) {
#pragma unroll
            for (int ii = 0; ii < 2; ++ii)
#pragma unroll
                for (int n = 0; n < 4; ++n)
                    xvg[ii][n] = xvN[ii][n];
        }
        __syncthreads();    // C: Wtb, staged buffers, bs ready
    }
}

extern "C" void kernel_launch(void* const* d_in, const int* in_sizes, int n_in,
                              void* d_out, int out_size, void* d_ws, size_t ws_size,
                              hipStream_t stream) {
    const float* xk         = (const float*)d_in[0];
    const float* xv         = (const float*)d_in[1];
    const float* weight     = (const float*)d_in[2];
    const float* bias       = (const float*)d_in[3];
    const float* gamma      = (const float*)d_in[4];
    const float* beta       = (const float*)d_in[5];
    const float* theta      = (const float*)d_in[6];
    const float* theta_bias = (const float*)d_in[7];
    const float* alpha      = (const float*)d_in[8];
    float* out = (float*)d_out;

    (void)hipFuncSetAttribute((const void*)ttt_kernel,
                              hipFuncAttributeMaxDynamicSharedMemorySize,
                              LDS_BYTES);
    ttt_kernel<<<64, 512, LDS_BYTES, stream>>>(xk, xv, weight, bias, gamma, beta,
                                               theta, theta_bias, alpha, out);
}